// Round 9
// baseline (249.670 us; speedup 1.0000x reference)
//
#include <hip/hip_runtime.h>

#define IYD 192
#define IZD 160
#define PLANE 30720        // IYD*IZD
#define VOLSZ 4915200      // 160*PLANE
#define YG 191
#define ZG 159

// LDS float layout (4344 floats = 17.4 KB):
// ZB[2v][15 rows][68] @0    : z-box of raw (+1-shift window [c-2,c+4] cap [1,159]), cols 0..63
// YB[2v][8 rows][76] @2040  : y-box of raw (rows [oy-2,oy+4] cap [1,191]), z rel 0..71 (base z0-4)
// TB[2v][8 rows][68] @3256  : z-box of YB (same +1-shift window), cols 0..63
#define ZBV 1020
#define ZBR 68
#define YBB 2040
#define YBV 608
#define YBR 76
#define TBB 3256
#define TBV 544
#define TBR 68
#define LDSF 4344

#define NVOX_INV (1.0f / 9657342.0f)   // 2*159*191*159

__device__ __forceinline__ float4 f4add(float4 a, float4 b) {
    return make_float4(a.x + b.x, a.y + b.y, a.z + b.z, a.w + b.w);
}
__device__ __forceinline__ float4 f4sub(float4 a, float4 b) {
    return make_float4(a.x - b.x, a.y - b.y, a.z - b.z, a.w - b.w);
}
__device__ __forceinline__ float4 f4scale(float4 a, float s) {
    return make_float4(a.x * s, a.y * s, a.z * s, a.w * s);
}

__global__ __launch_bounds__(512, 4) void grad_sim_v9(
    const float* __restrict__ Ii, const float* __restrict__ Ji,
    float* __restrict__ out)
{
    __shared__ __align__(16) float lds[LDSF];
    const int tid = threadIdx.x;
    const int y0 = (int)blockIdx.x * 8;
    const int z0 = (int)blockIdx.y * 64;
    const int seg = blockIdx.z % 6;
    const int bat = blockIdx.z / 6;
    const int s0 = seg * 27;
    const int a0 = (seg == 0) ? 0 : (s0 - 3);
    const int aLast = (seg == 5) ? 159 : (s0 + 30);

    const float* __restrict__ bI = Ii + (size_t)bat * VOLSZ;
    const float* __restrict__ bJ = Ji + (size_t)bat * VOLSZ;

    // ---- E1 decode (lanes 0..239): (v, row 0..14, oct 0..7) -> ZB ----
    const bool doZB = tid < 240;
    {
    }
    const int e1t = doZB ? tid : 0;
    const int e1v = e1t / 120;
    const int e1r = (e1t % 120) >> 3;
    const int e1o = e1t & 7;
    const int e1iy = y0 - 3 + e1r;
    const float e1my = (e1iy >= 0 && e1iy <= 191) ? 1.f : 0.f;
    const int e1yc = min(max(e1iy, 0), 191);
    const float* e1p0; const float* e1p1; const float* e1p2; const float* e1p3;
    float e1m0, e1m1, e1m2, e1m3;
    {
        const float* vb = (e1v ? bJ : bI) + e1yc * IZD;
        int zb;
        zb = z0 + 8 * e1o - 4;
        e1m0 = ((zb >= 0) && (zb + 3 <= 159)) ? e1my : 0.f;
        e1p0 = vb + min(max(zb, 0), 156);
        zb += 4;
        e1m1 = ((zb >= 0) && (zb + 3 <= 159)) ? e1my : 0.f;
        e1p1 = vb + min(max(zb, 0), 156);
        zb += 4;
        e1m2 = ((zb >= 0) && (zb + 3 <= 159)) ? e1my : 0.f;
        e1p2 = vb + min(max(zb, 0), 156);
        zb += 4;
        e1m3 = ((zb >= 0) && (zb + 3 <= 159)) ? e1my : 0.f;
        e1p3 = vb + min(max(zb, 0), 156);
    }
    const bool e1zlo = (z0 == 0) && (e1o == 0);
    const int e1wr = e1v * ZBV + e1r * ZBR + 8 * e1o;

    // ---- E2a decode (lanes 384..455): (v, quad 0..17, half) -> YB ----
    const int t2 = tid - 384;
    const bool doYB = (t2 >= 0) && (t2 < 72);
    const int t2s = doYB ? t2 : 0;
    const int yv = t2s / 36;
    const int r36 = t2s % 36;
    const int yq = r36 >> 1;
    const int yh = r36 & 1;
    int yoff[10]; float ymk[10];
    const float* ybase;
    {
        const int yzb = z0 - 4 + 4 * yq;
        const bool yokq = (yzb >= 0) && (yzb + 3 <= 159);
        ybase = (yv ? bJ : bI) + min(max(yzb, 0), 156);
#pragma unroll
        for (int i = 0; i < 10; ++i) {
            int iy = y0 + (yh ? 2 : -2) + i;
            ymk[i] = (yokq && iy >= 1 && iy <= 191) ? 1.f : 0.f;
            yoff[i] = min(max(iy, 0), 191) * IZD;
        }
    }
    const int ywr = YBB + yv * YBV + (yh * 4) * YBR + 4 * yq;

    // ---- E2b decode (lanes 0..127): (v, row 0..7, oct 0..7): YB -> TB ----
    const bool doTB = tid < 128;
    const int bv = tid >> 6;
    const int br = (tid >> 3) & 7;
    const int bo = tid & 7;
    const bool tbzlo = (z0 == 0) && (bo == 0);
    const int tbRd = YBB + bv * YBV + br * YBR + 8 * bo;
    const int tbWr = TBB + bv * TBV + br * TBR + 8 * bo;

    // ---- E3 per-thread column ----
    const int oy = tid >> 6;
    const int oz = tid & 63;
    const int ygl = y0 + oy;
    const int vmax = min(3, 190 - ygl);
    const int vmin = max(-3, -ygl);
    const int oVhi = (oy + vmax + 4) * ZBR + oz;
    const int oVlo = (oy + vmin + 3) * ZBR + oz;
    const int oT = TBB + oy * TBR + oz;
    const int relHi = (z0 == 128) ? min(oz + 8, 35) : (oz + 8);
    const int relLo = max(oz + 1, (z0 == 0) ? 4 : 0);
    const int oWhi = YBB + oy * YBR + relHi;
    const int oWlo = YBB + oy * YBR + relLo;
    const bool okyz = (ygl < YG) && ((z0 + oz) < ZG);

    // x rings (static indices only)
    float Tr[2][8], Vr[2][8], Wr[2][8], Sdy[2], Sdz[2];
#pragma unroll
    for (int v = 0; v < 2; ++v) {
#pragma unroll
        for (int j = 0; j < 8; ++j) { Tr[v][j] = 0.f; Vr[v][j] = 0.f; Wr[v][j] = 0.f; }
        Sdy[v] = 0.f; Sdz[v] = 0.f;
    }
    float acc = 0.f;

    // ---- prologue: issue E1 prefetch of plane a0 ----
    float4 P0 = make_float4(0, 0, 0, 0), P1 = P0, P2 = P0, P3 = P0;
    if (doZB) {
        const size_t pb = (size_t)a0 * PLANE;
        P0 = *(const float4*)(e1p0 + pb);
        P1 = *(const float4*)(e1p1 + pb);
        P2 = *(const float4*)(e1p2 + pb);
        P3 = *(const float4*)(e1p3 + pb);
    }

    for (int ag = (a0 & ~7); ag <= aLast; ag += 8) {
#pragma unroll
        for (int u = 0; u < 8; ++u) {
            const int a = ag + u;
            if (a < a0 || a > aLast) continue;   // uniform

            // ---- E1: z-box of raw plane a (from prefetched regs) -> ZB ----
            if (doZB) {
                float C[16];
                ((float4*)C)[0] = f4scale(P0, e1m0);
                ((float4*)C)[1] = f4scale(P1, e1m1);
                ((float4*)C)[2] = f4scale(P2, e1m2);
                ((float4*)C)[3] = f4scale(P3, e1m3);
                if (a + 1 <= aLast) {          // issue next plane
                    const size_t pb = (size_t)(a + 1) * PLANE;
                    P0 = *(const float4*)(e1p0 + pb);
                    P1 = *(const float4*)(e1p1 + pb);
                    P2 = *(const float4*)(e1p2 + pb);
                    P3 = *(const float4*)(e1p3 + pb);
                }
                if (e1zlo) C[4] = 0.f;         // exclude raw z=0 (gradient samples w+1)
                float Z[8];
                float w = C[2] + C[3] + C[4] + C[5] + C[6] + C[7] + C[8];
                Z[0] = w;
#pragma unroll
                for (int m = 1; m < 8; ++m) { w += C[m + 8] - C[m + 1]; Z[m] = w; }
                float4* zb = (float4*)&lds[e1wr];
                zb[0] = make_float4(Z[0], Z[1], Z[2], Z[3]);
                zb[1] = make_float4(Z[4], Z[5], Z[6], Z[7]);
            }

            // ---- E2a: y-box of raw plane a (direct global) -> YB ----
            if (doYB) {
                const size_t pb = (size_t)a * PLANE;
                float4 R[10];
#pragma unroll
                for (int i = 0; i < 10; ++i)
                    R[i] = f4scale(*(const float4*)(ybase + pb + yoff[i]), ymk[i]);
                float4 w = f4add(f4add(f4add(R[0], R[1]), f4add(R[2], R[3])),
                                 f4add(f4add(R[4], R[5]), R[6]));
                *(float4*)&lds[ywr] = w;
#pragma unroll
                for (int m = 1; m < 4; ++m) {
                    w = f4add(w, f4sub(R[m + 6], R[m - 1]));
                    *(float4*)&lds[ywr + m * YBR] = w;
                }
            }
            __syncthreads();

            // ---- E2b: z-box of YB -> TB ----
            if (doTB) {
                float C[16];
                const float4* yb = (const float4*)&lds[tbRd];
#pragma unroll
                for (int q = 0; q < 4; ++q) ((float4*)C)[q] = yb[q];
                if (tbzlo) { C[2] = 0.f; C[3] = 0.f; C[4] = 0.f; }
                float Z[8];
                float w = C[2] + C[3] + C[4] + C[5] + C[6] + C[7] + C[8];
                Z[0] = w;
#pragma unroll
                for (int m = 1; m < 8; ++m) { w += C[m + 8] - C[m + 1]; Z[m] = w; }
                float4* tb = (float4*)&lds[tbWr];
                tb[0] = make_float4(Z[0], Z[1], Z[2], Z[3]);
                tb[1] = make_float4(Z[4], Z[5], Z[6], Z[7]);
            }
            __syncthreads();

            // ---- E3: ring push + emit x = a-4 ----
            {
                float tI = lds[oT];
                float tJ = lds[oT + TBV];
                float vI = lds[oVhi] - lds[oVlo];
                float vJ = lds[oVhi + ZBV] - lds[oVlo + ZBV];
                float wI = lds[oWhi] - lds[oWlo];
                float wJ = lds[oWhi + YBV] - lds[oWlo + YBV];
                if (a == a0) { vI = 0.f; vJ = 0.f; wI = 0.f; wJ = 0.f; }
                const int p = u;                 // = a & 7, compile-time
                const int p1 = (u + 1) & 7;
                float hdxI = tI - Tr[0][p1];
                float hdxJ = tJ - Tr[1][p1];
                Sdy[0] += vI - Vr[0][p1]; Vr[0][p] = vI;
                Sdy[1] += vJ - Vr[1][p1]; Vr[1][p] = vJ;
                Sdz[0] += wI - Wr[0][p1]; Wr[0][p] = wI;
                Sdz[1] += wJ - Wr[1][p1]; Wr[1][p] = wJ;
                Tr[0][p] = tI; Tr[1][p] = tJ;
                if (p == 0 && a == 0) {   // seed clamped prefix T[0] for x=0,1,2
                    Tr[0][5] = tI; Tr[0][6] = tI; Tr[0][7] = tI;
                    Tr[1][5] = tJ; Tr[1][6] = tJ; Tr[1][7] = tJ;
                }
                if (a >= s0 + 4) {
                    float cross = fabsf(hdxI * hdxJ + Sdy[0] * Sdy[1] + Sdz[0] * Sdz[1]) + 0.01f;
                    float dI = hdxI * hdxI + Sdy[0] * Sdy[0] + Sdz[0] * Sdz[0] + 0.01f;
                    float dJ = hdxJ * hdxJ + Sdy[1] * Sdy[1] + Sdz[1] * Sdz[1] + 0.01f;
                    float val = cross * rsqrtf(dI * dJ);
                    if (okyz) acc += val;
                }
            }
            __syncthreads();
        }
    }

    // ---- register-only tail (seg 5): x = 156,157,158 ----
    if (seg == 5) {
#pragma unroll
        for (int tt = 0; tt < 3; ++tt) {
            const int sl = tt + 1;               // planes 153,154,155
            float hdxI = Tr[0][7] - Tr[0][sl];   // T[159] - T[x-3]
            float hdxJ = Tr[1][7] - Tr[1][sl];
            Sdy[0] -= Vr[0][sl]; Sdy[1] -= Vr[1][sl];
            Sdz[0] -= Wr[0][sl]; Sdz[1] -= Wr[1][sl];
            float cross = fabsf(hdxI * hdxJ + Sdy[0] * Sdy[1] + Sdz[0] * Sdz[1]) + 0.01f;
            float dI = hdxI * hdxI + Sdy[0] * Sdy[0] + Sdz[0] * Sdz[0] + 0.01f;
            float dJ = hdxJ * hdxJ + Sdy[1] * Sdy[1] + Sdz[1] * Sdz[1] + 0.01f;
            float val = cross * rsqrtf(dI * dJ);
            if (okyz) acc += val;
        }
    }

    // ---- block reduce + atomic ----
#pragma unroll
    for (int off = 32; off > 0; off >>= 1) acc += __shfl_down(acc, off, 64);
    __syncthreads();
    if ((tid & 63) == 0) lds[tid >> 6] = acc;
    __syncthreads();
    if (tid == 0) {
        float total = 0.f;
#pragma unroll
        for (int wv = 0; wv < 8; ++wv) total += lds[wv];
        atomicAdd(out, total * NVOX_INV);
    }
}

extern "C" void kernel_launch(void* const* d_in, const int* in_sizes, int n_in,
                              void* d_out, int out_size, void* d_ws, size_t ws_size,
                              hipStream_t stream) {
    const float* Ii = (const float*)d_in[0];
    const float* Ji = (const float*)d_in[1];
    float* out = (float*)d_out;
    hipMemsetAsync(d_out, 0, sizeof(float) * (out_size > 0 ? out_size : 1), stream);
    dim3 grid(24, 3, 12);   // y-tiles(8) x z-tiles(64) x (6 x-segments * 2 batches)
    grad_sim_v9<<<grid, dim3(512), 0, stream>>>(Ii, Ji, out);
}

// Round 10
// 98.911 us; speedup vs baseline: 2.5242x; 2.5242x over previous
//
#include <hip/hip_runtime.h>

#define IYD 192
#define IZD 160
#define PLANE 30720        // IYD*IZD
#define VOLSZ 4915200      // 160*PLANE
#define YG 191
#define ZG 159

// LDS float layout (5160 floats = 20640 B), bank-rotated buffers:
// raw[2v][15 rows][44] @0 : z rel 0..39 = global z0-4 .. z0+35 (quad-granular)
// ZD @1320, 4 bufs step 668: Z_I,Z_J,D_I,D_J each [15 rows][44] (cols 0..35 used)
//   Z = z-box of raw (+1-shift window), D = raw[min(w+4,159)]-raw[max(w-3,0)]
// SB @3984, 4 bufs step 296: T_I,T_J,W_I,W_J each [8 oy][36] (cols 0..31 used)
//   T = y-box of Z, W = y-box of D
#define RAWV 660
#define RAWR 44
#define ZD0 1320
#define ZDS 668
#define ZDR2 44
#define SB0 3984
#define SBS 296
#define SBR 36
#define LDSF 5160

#define NVOX_INV (1.0f / 9657342.0f)   // 2*159*191*159

__device__ __forceinline__ float4 f4scale(float4 a, float s) {
    return make_float4(a.x * s, a.y * s, a.z * s, a.w * s);
}
__device__ __forceinline__ float4 f4add(float4 a, float4 b) {
    return make_float4(a.x + b.x, a.y + b.y, a.z + b.z, a.w + b.w);
}
__device__ __forceinline__ float4 f4sub(float4 a, float4 b) {
    return make_float4(a.x - b.x, a.y - b.y, a.z - b.z, a.w - b.w);
}

__global__ __launch_bounds__(256, 4) void grad_sim_v10(
    const float* __restrict__ Ii, const float* __restrict__ Ji,
    float* __restrict__ out)
{
    __shared__ __align__(16) float lds[LDSF];
    const int tid = threadIdx.x;
    const int z0 = (int)blockIdx.x * 32;
    const int y0 = (int)blockIdx.y * 8;
    const int seg = blockIdx.z & 3;
    const int bat = blockIdx.z >> 2;
    const int s0 = seg * 40;
    const int a0 = (seg == 0) ? 0 : (s0 - 3);
    const int aLast = (seg == 3) ? 159 : (s0 + 43);

    const float* __restrict__ bI = Ii + (size_t)bat * VOLSZ;
    const float* __restrict__ bJ = Ji + (size_t)bat * VOLSZ;

    // ---- per-thread float4 halo-load tasks: 2v x 15 rows x 10 quads = 300 ----
    const float* gq0; const float* gq1;
    int lq0, lq1; float mq0, mq1;
    {
        int q = tid;
        int v = q / 150; int rr = q - v * 150;
        int row = rr / 10; int qd = rr - row * 10;
        int iy = y0 - 3 + row; int izb = z0 - 4 + 4 * qd;
        bool ok = ((unsigned)iy < IYD) && (izb >= 0) && (izb + 3 <= 159);
        int iyc = min(max(iy, 0), IYD - 1); int izc = min(max(izb, 0), 156);
        gq0 = (v ? bJ : bI) + (iyc * IZD + izc);
        lq0 = v * RAWV + row * RAWR + 4 * qd;
        mq0 = ok ? 1.f : 0.f;
    }
    {
        int q = 256 + tid;
        int v = q / 150; int rr = q - v * 150;
        int row = rr / 10; int qd = rr - row * 10;
        int iy = y0 - 3 + row; int izb = z0 - 4 + 4 * qd;
        bool ok = ((unsigned)iy < IYD) && (izb >= 0) && (izb + 3 <= 159);
        int iyc = min(max(iy, 0), IYD - 1); int izc = min(max(izb, 0), 156);
        gq1 = (v ? bJ : bI) + (iyc * IZD + izc);
        lq1 = v * RAWV + row * RAWR + 4 * qd;
        mq1 = ok ? 1.f : 0.f;
    }

    // ---- E1 decode (120 lanes): (vol, row 0..14, zq 0..3) ----
    const int zv = tid / 60;
    const int zrr = tid - 60 * zv;
    const int zr = zrr >> 2;
    const int zq = zrr & 3;
    const bool doZ = tid < 120;
    const bool zlo = (z0 == 0) && (zq == 0);
    const bool zhi = (z0 == 128) && (zq == 3);
    const int rawRd = zv * RAWV + zr * RAWR + 8 * zq;
    const int zdWr = zv * ZDS + zr * ZDR2 + 8 * zq;   // from ZD0 (Z) / ZD0+2*ZDS (D)

    // ---- E2 decode (64 lanes, branchless): (half, zq 0..7, f, v) ----
    const int e2h = tid & 1;
    const int e2c = tid >> 1;
    const int e2zq = e2c & 7;
    const int e2f = (e2c >> 3) & 1;
    const int e2v = e2c >> 4;
    const bool doY = tid < 64;
    const int e2k = e2f * 2 + e2v;                    // Z_I,Z_J,D_I,D_J
    const int e2rb = ZD0 + e2k * ZDS + (1 + 4 * e2h) * ZDR2 + 4 * e2zq;
    const int e2wb = SB0 + e2k * SBS + (4 * e2h) * SBR + 4 * e2zq;
    float e2m[10];
#pragma unroll
    for (int i = 0; i < 10; ++i) {
        int iy = y0 - 2 + 4 * e2h + i;
        e2m[i] = (iy >= 1 && iy <= 191) ? 1.f : 0.f;
    }

    // ---- E3 per-thread column ----
    const int oy = tid >> 5;
    const int oz = tid & 31;
    const int ygl = y0 + oy;
    const int vmax = min(3, 190 - ygl);
    const int vmin = max(-3, -ygl);
    const int oVhi = ZD0 + (oy + vmax + 4) * ZDR2 + oz;
    const int oVlo = ZD0 + (oy + vmin + 3) * ZDR2 + oz;
    const int oT = SB0 + oy * SBR + oz;
    const int oW = SB0 + 2 * SBS + oy * SBR + oz;
    const bool okyz = (ygl < YG) && ((z0 + oz) < ZG);

    // x rings (static indices only)
    float Tr[2][8], Vr[2][8], Wr[2][8], Sdy[2], Sdz[2];
#pragma unroll
    for (int v = 0; v < 2; ++v) {
#pragma unroll
        for (int j = 0; j < 8; ++j) { Tr[v][j] = 0.f; Vr[v][j] = 0.f; Wr[v][j] = 0.f; }
        Sdy[v] = 0.f; Sdz[v] = 0.f;
    }
    float acc = 0.f;

    // ---- prologue: land raw plane a0 ----
    {
        const size_t pb = (size_t)a0 * PLANE;
        float4 t0 = f4scale(*(const float4*)(gq0 + pb), mq0);
        *(float4*)&lds[lq0] = t0;
        if (tid < 44) {
            float4 t1 = f4scale(*(const float4*)(gq1 + pb), mq1);
            *(float4*)&lds[lq1] = t1;
        }
    }
    __syncthreads();

    for (int ag = (a0 & ~7); ag <= aLast; ag += 8) {
#pragma unroll
        for (int u = 0; u < 8; ++u) {
            const int a = ag + u;
            if (a < a0 || a > aLast) continue;   // uniform

            // ---- issue prefetch of plane a+1 ----
            const bool dof = (a + 1) <= aLast;
            float4 pf0, pf1;
            if (dof) {
                const size_t pb = (size_t)(a + 1) * PLANE;
                pf0 = *(const float4*)(gq0 + pb);
                if (tid < 44) pf1 = *(const float4*)(gq1 + pb);
            }

            // ---- E1: z-stage plane a -> Z/D buffers ----
            if (doZ) {
                float C[16];
                const float4* rb = (const float4*)&lds[rawRd];
#pragma unroll
                for (int q = 0; q < 4; ++q) ((float4*)C)[q] = rb[q];
                float D[8];
#pragma unroll
                for (int i = 0; i < 8; ++i) D[i] = C[i + 8] - C[i + 1];
                if (zlo) { D[0] = C[8] - C[4]; D[1] = C[9] - C[4]; D[2] = C[10] - C[4]; }
                if (zhi) { D[4] = C[11] - C[5]; D[5] = C[11] - C[6];
                           D[6] = C[11] - C[7]; D[7] = C[11] - C[8]; }
                if (zlo) { C[2] = 0.f; C[3] = 0.f; C[4] = 0.f; }
                float Z[8];
                float w = C[2] + C[3] + C[4] + C[5] + C[6] + C[7] + C[8];
                Z[0] = w;
#pragma unroll
                for (int m = 1; m < 8; ++m) { w += C[m + 8] - C[m + 1]; Z[m] = w; }
                float4* zb = (float4*)&lds[ZD0 + zdWr];
                zb[0] = make_float4(Z[0], Z[1], Z[2], Z[3]);
                zb[1] = make_float4(Z[4], Z[5], Z[6], Z[7]);
                float4* db = (float4*)&lds[ZD0 + 2 * ZDS + zdWr];
                db[0] = make_float4(D[0], D[1], D[2], D[3]);
                db[1] = make_float4(D[4], D[5], D[6], D[7]);
            }
            __syncthreads();

            // ---- E2: branchless y-slide (b128 over z) -> T/W ----
            if (doY) {
                float4 r[10];
#pragma unroll
                for (int i = 0; i < 10; ++i)
                    r[i] = f4scale(*(const float4*)&lds[e2rb + i * ZDR2], e2m[i]);
                float4 w = f4add(f4add(f4add(r[0], r[1]), f4add(r[2], r[3])),
                                 f4add(f4add(r[4], r[5]), r[6]));
                *(float4*)&lds[e2wb] = w;
#pragma unroll
                for (int m = 1; m < 4; ++m) {
                    w = f4add(w, f4sub(r[m + 6], r[m - 1]));
                    *(float4*)&lds[e2wb + m * SBR] = w;
                }
            }
            __syncthreads();

            // ---- E3: ring push + emit x = a-4 ----
            {
                float tI = lds[oT];
                float tJ = lds[oT + SBS];
                float wI = lds[oW];
                float wJ = lds[oW + SBS];
                float vI = lds[oVhi] - lds[oVlo];
                float vJ = lds[oVhi + ZDS] - lds[oVlo + ZDS];
                if (a == a0) { vI = 0.f; vJ = 0.f; wI = 0.f; wJ = 0.f; }
                const int p = u;                 // = a & 7, compile-time
                const int p1 = (u + 1) & 7;
                float hdxI = tI - Tr[0][p1];
                float hdxJ = tJ - Tr[1][p1];
                Sdy[0] += vI - Vr[0][p1]; Vr[0][p] = vI;
                Sdy[1] += vJ - Vr[1][p1]; Vr[1][p] = vJ;
                Sdz[0] += wI - Wr[0][p1]; Wr[0][p] = wI;
                Sdz[1] += wJ - Wr[1][p1]; Wr[1][p] = wJ;
                Tr[0][p] = tI; Tr[1][p] = tJ;
                if (p == 0 && a == 0) {   // seed clamped prefix T[0] for x=0,1,2
                    Tr[0][5] = tI; Tr[0][6] = tI; Tr[0][7] = tI;
                    Tr[1][5] = tJ; Tr[1][6] = tJ; Tr[1][7] = tJ;
                }
                if (a >= s0 + 4) {
                    float cross = fabsf(hdxI * hdxJ + Sdy[0] * Sdy[1] + Sdz[0] * Sdz[1]) + 0.01f;
                    float dI = hdxI * hdxI + Sdy[0] * Sdy[0] + Sdz[0] * Sdz[0] + 0.01f;
                    float dJ = hdxJ * hdxJ + Sdy[1] * Sdy[1] + Sdz[1] * Sdz[1] + 0.01f;
                    float val = cross * rsqrtf(dI * dJ);
                    if (okyz) acc += val;
                }
            }

            // ---- land prefetch into raw (E1 of plane a is done) ----
            if (dof) {
                *(float4*)&lds[lq0] = f4scale(pf0, mq0);
                if (tid < 44) *(float4*)&lds[lq1] = f4scale(pf1, mq1);
            }
            __syncthreads();
        }
    }

    // ---- register-only tail (seg 3): x = 156,157,158 ----
    if (seg == 3) {
#pragma unroll
        for (int tt = 0; tt < 3; ++tt) {
            const int sl = tt + 1;               // planes 153,154,155
            float hdxI = Tr[0][7] - Tr[0][sl];   // T[159] - T[x-3]
            float hdxJ = Tr[1][7] - Tr[1][sl];
            Sdy[0] -= Vr[0][sl]; Sdy[1] -= Vr[1][sl];
            Sdz[0] -= Wr[0][sl]; Sdz[1] -= Wr[1][sl];
            float cross = fabsf(hdxI * hdxJ + Sdy[0] * Sdy[1] + Sdz[0] * Sdz[1]) + 0.01f;
            float dI = hdxI * hdxI + Sdy[0] * Sdy[0] + Sdz[0] * Sdz[0] + 0.01f;
            float dJ = hdxJ * hdxJ + Sdy[1] * Sdy[1] + Sdz[1] * Sdz[1] + 0.01f;
            float val = cross * rsqrtf(dI * dJ);
            if (okyz) acc += val;
        }
    }

    // ---- block reduce + atomic ----
#pragma unroll
    for (int off = 32; off > 0; off >>= 1) acc += __shfl_down(acc, off, 64);
    __syncthreads();
    if ((tid & 63) == 0) lds[tid >> 6] = acc;
    __syncthreads();
    if (tid == 0)
        atomicAdd(out, (lds[0] + lds[1] + lds[2] + lds[3]) * NVOX_INV);
}

extern "C" void kernel_launch(void* const* d_in, const int* in_sizes, int n_in,
                              void* d_out, int out_size, void* d_ws, size_t ws_size,
                              hipStream_t stream) {
    const float* Ii = (const float*)d_in[0];
    const float* Ji = (const float*)d_in[1];
    float* out = (float*)d_out;
    hipMemsetAsync(d_out, 0, sizeof(float) * (out_size > 0 ? out_size : 1), stream);
    dim3 grid(5, 24, 8);   // z-tiles(32) x y-tiles(8) x (4 x-segments * 2 batches)
    grad_sim_v10<<<grid, dim3(256), 0, stream>>>(Ii, Ji, out);
}

// Round 11
// 96.759 us; speedup vs baseline: 2.5803x; 1.0222x over previous
//
#include <hip/hip_runtime.h>

#define IYD 192
#define IZD 160
#define PLANE 30720        // IYD*IZD
#define VOLSZ 4915200      // 160*PLANE
#define YG 191
#define ZG 159

// LDS float layout (3196 floats = 12784 B), v7 bank residues preserved:
// ZB @12   [2v][15][36] : z-box of raw (+1-shift window)   (12 mod 32 = v7's 1324)
// DB @1092 [2v][15][36] : raw[min(w+4,159)]-raw[max(w-3,0)] (4 mod 32 = v7's 2404)
// TB @2172 [2v][8][32]  : y-box of ZB                      (28 mod 32 = v7's 3484)
// WB @2684 [2v][8][32]  : y-box of DB                      (28 mod 32 = v7's 3996)
#define ZBB 12
#define ZDV 540
#define ZDR 36
#define DBB 1092
#define TBB 2172
#define WBB 2684
#define LDSF 3196

#define NVOX_INV (1.0f / 9657342.0f)   // 2*159*191*159

__device__ __forceinline__ float4 f4scale(float4 a, float s) {
    return make_float4(a.x * s, a.y * s, a.z * s, a.w * s);
}

__global__ __launch_bounds__(256, 4) void grad_sim_v11(
    const float* __restrict__ Ii, const float* __restrict__ Ji,
    float* __restrict__ out)
{
    __shared__ __align__(16) float lds[LDSF];
    const int tid = threadIdx.x;
    const int z0 = (int)blockIdx.x * 32;
    const int y0 = (int)blockIdx.y * 8;
    const int seg = blockIdx.z & 3;
    const int bat = blockIdx.z >> 2;
    const int s0 = seg * 40;
    const int a0 = (seg == 0) ? 0 : (s0 - 3);
    const int aLast = (seg == 3) ? 159 : (s0 + 43);

    const float* __restrict__ bI = Ii + (size_t)bat * VOLSZ;
    const float* __restrict__ bJ = Ji + (size_t)bat * VOLSZ;

    // ---- E1 decode (120 lanes): (vol, row 0..14, zq 0..3), input direct from global ----
    const bool doZ = tid < 120;
    const int e1t = doZ ? tid : 0;
    const int e1v = e1t / 60;
    const int e1rr = e1t - 60 * e1v;
    const int e1r = e1rr >> 2;
    const int e1q = e1rr & 3;
    const bool zlo = (z0 == 0) && (e1q == 0);
    const bool zhi = (z0 == 128) && (e1q == 3);
    const int zdWr = e1v * ZDV + e1r * ZDR + 8 * e1q;
    const float* p0; const float* p1; const float* p2; const float* p3;
    float m0, m1, m2, m3;
    {
        const int iy = y0 - 3 + e1r;
        const float myk = ((unsigned)iy < IYD) ? 1.f : 0.f;
        const float* vb = (e1v ? bJ : bI) + min(max(iy, 0), IYD - 1) * IZD;
        int zb = z0 - 4 + 8 * e1q;
        m0 = ((zb >= 0) && (zb <= 156)) ? myk : 0.f;
        p0 = vb + min(max(zb, 0), 156);
        zb += 4;
        m1 = ((zb >= 0) && (zb <= 156)) ? myk : 0.f;
        p1 = vb + min(max(zb, 0), 156);
        zb += 4;
        m2 = ((zb >= 0) && (zb <= 156)) ? myk : 0.f;
        p2 = vb + min(max(zb, 0), 156);
        zb += 4;
        m3 = ((zb >= 0) && (zb <= 156)) ? myk : 0.f;
        p3 = vb + min(max(zb, 0), 156);
    }

    // ---- E2 decode (64 lanes): (half, zq 0..7, f, v) -- v7 verbatim ----
    const int e2half = tid & 1;
    const int e2c = tid >> 1;
    const int e2zq = e2c & 7;
    const int e2f = (e2c >> 3) & 1;
    const int e2v = e2c >> 4;
    const bool doY = tid < 64;
    const int e2base = (e2f ? DBB : ZBB) + e2v * ZDV + 4 * e2zq;
    const int e2out = (e2f ? WBB : TBB) + e2v * 256 + 4 * e2zq;
    const float mlo = (y0 == 0) ? 0.f : 1.f;
    const float mhi = (y0 == 184) ? 0.f : 1.f;

    // ---- E3 per-thread column -- v7 verbatim ----
    const int oy = tid >> 5;
    const int oz = tid & 31;
    const int ygl = y0 + oy;
    const int vmax = min(3, 190 - ygl);
    const int vmin = max(-3, -ygl);
    const int vHiI = ZBB + (oy + vmax + 4) * ZDR + oz;
    const int vLoI = ZBB + (oy + vmin + 3) * ZDR + oz;
    const bool okyz = (ygl < YG) && ((z0 + oz) < ZG);

    // x rings (static indices only)
    float Tr[2][8], Vr[2][8], Wr[2][8], Sdy[2], Sdz[2];
#pragma unroll
    for (int v = 0; v < 2; ++v) {
#pragma unroll
        for (int j = 0; j < 8; ++j) { Tr[v][j] = 0.f; Vr[v][j] = 0.f; Wr[v][j] = 0.f; }
        Sdy[v] = 0.f; Sdz[v] = 0.f;
    }
    float acc = 0.f;

    // ---- prologue: prefetch plane a0 into registers ----
    float4 P0 = make_float4(0, 0, 0, 0), P1 = P0, P2 = P0, P3 = P0;
    if (doZ) {
        const size_t pb = (size_t)a0 * PLANE;
        P0 = *(const float4*)(p0 + pb);
        P1 = *(const float4*)(p1 + pb);
        P2 = *(const float4*)(p2 + pb);
        P3 = *(const float4*)(p3 + pb);
    }

    for (int ag = (a0 & ~7); ag <= aLast; ag += 8) {
#pragma unroll
        for (int u = 0; u < 8; ++u) {
            const int a = ag + u;
            if (a < a0 || a > aLast) continue;   // uniform

            // ---- E1: z-stage plane a from regs -> Z/D; issue prefetch a+1 ----
            if (doZ) {
                float C[16];
                ((float4*)C)[0] = f4scale(P0, m0);
                ((float4*)C)[1] = f4scale(P1, m1);
                ((float4*)C)[2] = f4scale(P2, m2);
                ((float4*)C)[3] = f4scale(P3, m3);
                if (a + 1 <= aLast) {
                    const size_t pb = (size_t)(a + 1) * PLANE;
                    P0 = *(const float4*)(p0 + pb);
                    P1 = *(const float4*)(p1 + pb);
                    P2 = *(const float4*)(p2 + pb);
                    P3 = *(const float4*)(p3 + pb);
                }
                float D[8];
#pragma unroll
                for (int i = 0; i < 8; ++i) D[i] = C[i + 8] - C[i + 1];
                if (zlo) { D[0] = C[8] - C[4]; D[1] = C[9] - C[4]; D[2] = C[10] - C[4]; }
                if (zhi) { D[4] = C[11] - C[5]; D[5] = C[11] - C[6];
                           D[6] = C[11] - C[7]; D[7] = C[11] - C[8]; }
                if (zlo) { C[2] = 0.f; C[3] = 0.f; C[4] = 0.f; }
                float Z[8];
                float w = C[2] + C[3] + C[4] + C[5] + C[6] + C[7] + C[8];
                Z[0] = w;
#pragma unroll
                for (int m = 1; m < 8; ++m) { w += C[m + 8] - C[m + 1]; Z[m] = w; }
                float4* zb = (float4*)&lds[ZBB + zdWr];
                zb[0] = make_float4(Z[0], Z[1], Z[2], Z[3]);
                zb[1] = make_float4(Z[4], Z[5], Z[6], Z[7]);
                float4* db = (float4*)&lds[DBB + zdWr];
                db[0] = make_float4(D[0], D[1], D[2], D[3]);
                db[1] = make_float4(D[4], D[5], D[6], D[7]);
            }
            __syncthreads();

            // ---- E2: y-slide (v7 verbatim) ----
            if (doY) {
                float4 r[11];
                const int r0 = e2half ? 4 : 1;
#pragma unroll
                for (int i = 0; i < 11; ++i)
                    r[i] = *(const float4*)&lds[e2base + (r0 + i) * ZDR];
                if (e2half == 0) {
                    r[0].x *= mlo; r[0].y *= mlo; r[0].z *= mlo; r[0].w *= mlo;
                    r[1].x *= mlo; r[1].y *= mlo; r[1].z *= mlo; r[1].w *= mlo;
                    r[2].x *= mlo; r[2].y *= mlo; r[2].z *= mlo; r[2].w *= mlo;
                    r[10].x *= mhi; r[10].y *= mhi; r[10].z *= mhi; r[10].w *= mhi;
                    float4 w;
                    w.x = r[0].x + r[1].x + r[2].x + r[3].x + r[4].x + r[5].x + r[6].x;
                    w.y = r[0].y + r[1].y + r[2].y + r[3].y + r[4].y + r[5].y + r[6].y;
                    w.z = r[0].z + r[1].z + r[2].z + r[3].z + r[4].z + r[5].z + r[6].z;
                    w.w = r[0].w + r[1].w + r[2].w + r[3].w + r[4].w + r[5].w + r[6].w;
                    *(float4*)&lds[e2out] = w;
#pragma unroll
                    for (int m = 1; m < 4; ++m) {
                        w.x += r[m + 6].x - r[m - 1].x;
                        w.y += r[m + 6].y - r[m - 1].y;
                        w.z += r[m + 6].z - r[m - 1].z;
                        w.w += r[m + 6].w - r[m - 1].w;
                        *(float4*)&lds[e2out + m * 32] = w;
                    }
                } else {
                    r[7].x *= mhi; r[7].y *= mhi; r[7].z *= mhi; r[7].w *= mhi;
                    r[8].x *= mhi; r[8].y *= mhi; r[8].z *= mhi; r[8].w *= mhi;
                    r[9].x *= mhi; r[9].y *= mhi; r[9].z *= mhi; r[9].w *= mhi;
                    r[10].x *= mhi; r[10].y *= mhi; r[10].z *= mhi; r[10].w *= mhi;
                    float4 w;
                    w.x = r[1].x + r[2].x + r[3].x + r[4].x + r[5].x + r[6].x + r[7].x;
                    w.y = r[1].y + r[2].y + r[3].y + r[4].y + r[5].y + r[6].y + r[7].y;
                    w.z = r[1].z + r[2].z + r[3].z + r[4].z + r[5].z + r[6].z + r[7].z;
                    w.w = r[1].w + r[2].w + r[3].w + r[4].w + r[5].w + r[6].w + r[7].w;
                    *(float4*)&lds[e2out + 4 * 32] = w;
#pragma unroll
                    for (int m = 1; m < 4; ++m) {
                        w.x += r[m + 7].x - r[m].x;
                        w.y += r[m + 7].y - r[m].y;
                        w.z += r[m + 7].z - r[m].z;
                        w.w += r[m + 7].w - r[m].w;
                        *(float4*)&lds[e2out + (4 + m) * 32] = w;
                    }
                }
            }
            __syncthreads();

            // ---- E3: ring push + emit x = a-4 (v7 verbatim) ----
            {
                float tI = lds[TBB + tid];
                float tJ = lds[TBB + 256 + tid];
                float wI = lds[WBB + tid];
                float wJ = lds[WBB + 256 + tid];
                float vI = lds[vHiI] - lds[vLoI];
                float vJ = lds[vHiI + ZDV] - lds[vLoI + ZDV];
                if (a == a0) { vI = 0.f; vJ = 0.f; wI = 0.f; wJ = 0.f; }
                const int p = u;                 // = a & 7, compile-time
                const int p1 = (u + 1) & 7;
                float hdxI = tI - Tr[0][p1];
                float hdxJ = tJ - Tr[1][p1];
                Sdy[0] += vI - Vr[0][p1]; Vr[0][p] = vI;
                Sdy[1] += vJ - Vr[1][p1]; Vr[1][p] = vJ;
                Sdz[0] += wI - Wr[0][p1]; Wr[0][p] = wI;
                Sdz[1] += wJ - Wr[1][p1]; Wr[1][p] = wJ;
                Tr[0][p] = tI; Tr[1][p] = tJ;
                if (p == 0 && a == 0) {   // seed clamped prefix T[0] for x=0,1,2
                    Tr[0][5] = tI; Tr[0][6] = tI; Tr[0][7] = tI;
                    Tr[1][5] = tJ; Tr[1][6] = tJ; Tr[1][7] = tJ;
                }
                if (a >= s0 + 4) {
                    float cross = fabsf(hdxI * hdxJ + Sdy[0] * Sdy[1] + Sdz[0] * Sdz[1]) + 0.01f;
                    float dI = hdxI * hdxI + Sdy[0] * Sdy[0] + Sdz[0] * Sdz[0] + 0.01f;
                    float dJ = hdxJ * hdxJ + Sdy[1] * Sdy[1] + Sdz[1] * Sdz[1] + 0.01f;
                    float val = cross * rsqrtf(dI * dJ);
                    if (okyz) acc += val;
                }
            }
            __syncthreads();
        }
    }

    // ---- register-only tail (seg 3): x = 156,157,158 ----
    if (seg == 3) {
#pragma unroll
        for (int tt = 0; tt < 3; ++tt) {
            const int sl = tt + 1;               // planes 153,154,155
            float hdxI = Tr[0][7] - Tr[0][sl];   // T[159] - T[x-3]
            float hdxJ = Tr[1][7] - Tr[1][sl];
            Sdy[0] -= Vr[0][sl]; Sdy[1] -= Vr[1][sl];
            Sdz[0] -= Wr[0][sl]; Sdz[1] -= Wr[1][sl];
            float cross = fabsf(hdxI * hdxJ + Sdy[0] * Sdy[1] + Sdz[0] * Sdz[1]) + 0.01f;
            float dI = hdxI * hdxI + Sdy[0] * Sdy[0] + Sdz[0] * Sdz[0] + 0.01f;
            float dJ = hdxJ * hdxJ + Sdy[1] * Sdy[1] + Sdz[1] * Sdz[1] + 0.01f;
            float val = cross * rsqrtf(dI * dJ);
            if (okyz) acc += val;
        }
    }

    // ---- block reduce + atomic ----
#pragma unroll
    for (int off = 32; off > 0; off >>= 1) acc += __shfl_down(acc, off, 64);
    __syncthreads();
    if ((tid & 63) == 0) lds[tid >> 6] = acc;
    __syncthreads();
    if (tid == 0)
        atomicAdd(out, (lds[0] + lds[1] + lds[2] + lds[3]) * NVOX_INV);
}

extern "C" void kernel_launch(void* const* d_in, const int* in_sizes, int n_in,
                              void* d_out, int out_size, void* d_ws, size_t ws_size,
                              hipStream_t stream) {
    const float* Ii = (const float*)d_in[0];
    const float* Ji = (const float*)d_in[1];
    float* out = (float*)d_out;
    hipMemsetAsync(d_out, 0, sizeof(float) * (out_size > 0 ? out_size : 1), stream);
    dim3 grid(5, 24, 8);   // z-tiles(32) x y-tiles(8) x (4 x-segments * 2 batches)
    grad_sim_v11<<<grid, dim3(256), 0, stream>>>(Ii, Ji, out);
}